// Round 5
// baseline (387.889 us; speedup 1.0000x reference)
//
#include <hip/hip_runtime.h>
#include <math.h>

#define NQ 6
#define DIM 64
#define NB 2             // elements per wave-iteration
#define PI_F 3.14159265358979323846f

typedef int i32x2 __attribute__((ext_vector_type(2)));

// ---------- DPP helpers ----------
template <int CTRL, int ROWM, bool BC>
__device__ __forceinline__ float dpp_add_src(float v) {
  int r = __builtin_amdgcn_update_dpp(0, __float_as_int(v), CTRL, ROWM, 0xF, BC);
  return __int_as_float(r);
}
template <int CTRL>
__device__ __forceinline__ float dpp_mov(float v) {
  int i = __float_as_int(v);
  return __int_as_float(__builtin_amdgcn_update_dpp(i, i, CTRL, 0xF, 0xF, false));
}

// sum over 64 lanes; valid in lane 63
__device__ __forceinline__ float red_sum(float v) {
  v += dpp_add_src<0x111, 0xF, true>(v);   // row_shr:1
  v += dpp_add_src<0x112, 0xF, true>(v);   // row_shr:2
  v += dpp_add_src<0x114, 0xF, true>(v);   // row_shr:4
  v += dpp_add_src<0x118, 0xF, true>(v);   // row_shr:8
  v += dpp_add_src<0x142, 0xA, false>(v);  // row_bcast:15 -> rows 1,3
  v += dpp_add_src<0x143, 0xC, false>(v);  // row_bcast:31 -> rows 2,3
  return v;
}
__device__ __forceinline__ float bcast63(float v) {
  return __int_as_float(__builtin_amdgcn_readlane(__float_as_int(v), 63));
}
__device__ __forceinline__ float rdlane(float v, int l) {
  return __int_as_float(__builtin_amdgcn_readlane(__float_as_int(v), l));
}

// ---------- xor-partner exchange for wire W (mask = 32>>W) ----------
template <int W>
__device__ __forceinline__ float shuf(float v, int lane) {
  if constexpr (W == 5) {        // xor 1: quad_perm [1,0,3,2]
    return dpp_mov<0xB1>(v);
  } else if constexpr (W == 4) { // xor 2: quad_perm [2,3,0,1]
    return dpp_mov<0x4E>(v);
  } else if constexpr (W == 3) { // xor 4: LDS swizzle
    return __int_as_float(__builtin_amdgcn_ds_swizzle(__float_as_int(v), 0x101F));
  } else if constexpr (W == 2) { // xor 8 == row_ror:8 within 16-lane rows
    return dpp_mov<0x128>(v);
  } else if constexpr (W == 1) { // xor 16: permlane16_swap (VALU)
#if __has_builtin(__builtin_amdgcn_permlane16_swap)
    i32x2 r = __builtin_amdgcn_permlane16_swap(__float_as_int(v),
                                               __float_as_int(v), false, false);
    return __int_as_float((lane & 16) ? r[0] : r[1]);
#else
    return __int_as_float(__builtin_amdgcn_ds_swizzle(__float_as_int(v), 0x401F));
#endif
  } else {                       // xor 32: permlane32_swap (VALU)
#if __has_builtin(__builtin_amdgcn_permlane32_swap)
    i32x2 r = __builtin_amdgcn_permlane32_swap(__float_as_int(v),
                                               __float_as_int(v), false, false);
    return __int_as_float((lane & 32) ? r[0] : r[1]);
#else
    return __shfl_xor(v, 32, 64);
#endif
  }
}

// ---------- one Rot gate on wire W applied to NB states ----------
// U = [[a, b], [-conj(b), conj(a)]]; c=(ar,ai,br,bi) wave-uniform (LDS bcast);
// sg = -1 on the |1> half of the wire, +1 on the |0> half.
template <int W>
__device__ __forceinline__ void gate2(float (&re)[NB], float (&im)[NB],
                                      float4 c, float sg, int lane) {
  const float ais = c.y * sg;
  const float brs = c.z * sg;
  #pragma unroll
  for (int r = 0; r < NB; ++r) {
    const float pr = shuf<W>(re[r], lane);
    const float pi = shuf<W>(im[r], lane);
    float nr = c.x * re[r];
    nr = fmaf(-ais, im[r], nr);
    nr = fmaf(brs, pr, nr);
    nr = fmaf(-c.w, pi, nr);
    float ni = c.x * im[r];
    ni = fmaf(ais, re[r], ni);
    ni = fmaf(brs, pi, ni);
    ni = fmaf(c.w, pr, ni);
    re[r] = nr; im[r] = ni;
  }
}

// composed source index for the CNOT ring of range r
__device__ __forceinline__ int cnot_src(int j, int r) {
  int i = j;
  #pragma unroll
  for (int w = 5; w >= 0; --w) {
    const int cm = 32 >> w;
    const int tm = 32 >> ((w + r) % NQ);
    if (i & cm) i ^= tm;
  }
  return i;
}

__global__ __launch_bounds__(256, 8) void qmaml_v5(
    const float* __restrict__ x,
    const float* __restrict__ W1,
    const float* __restrict__ b1,
    const float* __restrict__ ln_g,
    const float* __restrict__ ln_b,
    const float* __restrict__ W2,
    const float* __restrict__ b2,
    const float* __restrict__ th_sh,
    const float* __restrict__ th_tk,
    const float* __restrict__ Wc,
    const float* __restrict__ bc,
    float* __restrict__ out,
    int B)
{
  __shared__ float w1t[64 * 64];    // w1t[k*64 + j] = W1[j][k]  (16 KiB)
  __shared__ float4 coef[18];       // gate coefficients (288 B)
  __shared__ float lc[14 * 64];     // per-lane consts (3.5 KiB):
                                    // 0=b1 1=ln_g 2=ln_b 3..8=W2 rows 9..13=g5

  const int tid = threadIdx.x;

  // ---- stage W1^T (reads coalesced; write conflicts are one-time) ----
  #pragma unroll
  for (int it = 0; it < 16; ++it) {
    const int idx = tid + it * 256;
    w1t[(idx & 63) * 64 + (idx >> 6)] = W1[idx];
  }
  // ---- gate coefficient table ----
  if (tid < 18) {
    const int layer = tid / 6, w = tid % 6;
    const float* th = (layer < 2) ? (th_sh + (layer * 6 + w) * 3)
                                  : (th_tk + w * 3);
    const float phi = th[0], the = th[1], om = th[2];
    float S, C;   sincosf(0.5f * the,        &S,  &C);
    float sS, cS; sincosf(0.5f * (om + phi), &sS, &cS);
    float sD, cD; sincosf(0.5f * (om - phi), &sD, &cD);
    coef[tid] = make_float4(C * cS, -C * sS, -S * cD, S * sD);
  }
  // ---- per-lane constant table (built by first wave) ----
  if (tid < 64) {
    lc[0 * 64 + tid] = b1[tid];
    lc[1 * 64 + tid] = ln_g[tid];
    lc[2 * 64 + tid] = ln_b[tid];
    #pragma unroll
    for (int m = 0; m < NQ; ++m) lc[(3 + m) * 64 + tid] = W2[m * DIM + tid];
    #pragma unroll
    for (int j = 0; j < 5; ++j) {
      float a = 0.0f;
      #pragma unroll
      for (int w = 0; w < NQ; ++w) {
        const float wc = Wc[j * NQ + w];
        a += (tid & (32 >> w)) ? -wc : wc;
      }
      lc[(9 + j) * 64 + tid] = a;
    }
  }
  __syncthreads();

  const int lane = tid & 63;
  const int wid = __builtin_amdgcn_readfirstlane(blockIdx.x * 4 + (tid >> 6));
  const int nw = gridDim.x * 4;

  // ---- minimal per-lane register preloads ----
  const float b2p = (lane < NB * NQ) ? b2[lane % NQ] : 0.0f;
  const float bcv = (lane < 5) ? bc[lane] : 0.0f;
  float sgn[NQ];
  #pragma unroll
  for (int w = 0; w < NQ; ++w) sgn[w] = (lane & (32 >> w)) ? -1.0f : 1.0f;
  const int pa1 = cnot_src(lane, 1) << 2;
  const int pa2 = cnot_src(lane, 2) << 2;

  for (int t0 = wid * NB; t0 < B; t0 += nw * NB) {
    // ---- Linear1 + ReLU for NB elements; W1 value read once per k ----
    const float* __restrict__ xr0 = x + (size_t)t0 * DIM;      // wave-uniform
    const float* __restrict__ xr1 = xr0 + ((t0 + 1 < B) ? DIM : 0);
    float acc0 = lc[0 * 64 + lane];
    float acc1 = acc0;
    #pragma unroll
    for (int k = 0; k < DIM; ++k) {
      const float wv = w1t[k * 64 + lane];
      acc0 = fmaf(wv, xr0[k], acc0);
      acc1 = fmaf(wv, xr1[k], acc1);
    }

    // ---- LayerNorm ----
    const float lgv = lc[1 * 64 + lane];
    const float lbv = lc[2 * 64 + lane];
    float h[NB];
    {
      const float hv0 = fmaxf(acc0, 0.0f);
      const float hv1 = fmaxf(acc1, 0.0f);
      const float s10 = bcast63(red_sum(hv0)) * (1.0f / DIM);
      const float s20 = bcast63(red_sum(hv0 * hv0)) * (1.0f / DIM);
      const float s11 = bcast63(red_sum(hv1)) * (1.0f / DIM);
      const float s21 = bcast63(red_sum(hv1 * hv1)) * (1.0f / DIM);
      const float rs0 = __builtin_amdgcn_rsqf(s20 - s10 * s10 + 1e-5f);
      const float rs1 = __builtin_amdgcn_rsqf(s21 - s11 * s11 + 1e-5f);
      h[0] = fmaf((hv0 - s10) * rs0, lgv, lbv);
      h[1] = fmaf((hv1 - s11) * rs1, lgv, lbv);
    }

    // ---- Linear2: pack the NB*6 angle sums into lanes 0..11 ----
    float y = 0.0f;
    #pragma unroll
    for (int m = 0; m < NQ; ++m) {
      const float wm = lc[(3 + m) * 64 + lane];
      const float s0 = bcast63(red_sum(wm * h[0]));
      const float s1 = bcast63(red_sum(wm * h[1]));
      y = (lane == 0 * NQ + m) ? s0 : y;
      y = (lane == 1 * NQ + m) ? s1 : y;
    }
    y += b2p;

    // ---- tanh + half-angle sincos: one evaluation for both elements ----
    const float e = __expf(2.0f * y);
    const float tz = fmaf(-2.0f, __builtin_amdgcn_rcpf(e + 1.0f), 1.0f);
    const float ha = (0.5f * PI_F) * tz;
    const float sv = __sinf(ha);
    const float cv = __cosf(ha);

    // ---- init product states (lane = basis index) ----
    float re[NB], im[NB];
    #pragma unroll
    for (int r = 0; r < NB; ++r) {
      float a = (lane & 32) ? rdlane(sv, r*NQ+0) : rdlane(cv, r*NQ+0);
      a *= (lane & 16) ? rdlane(sv, r*NQ+1) : rdlane(cv, r*NQ+1);
      a *= (lane &  8) ? rdlane(sv, r*NQ+2) : rdlane(cv, r*NQ+2);
      a *= (lane &  4) ? rdlane(sv, r*NQ+3) : rdlane(cv, r*NQ+3);
      a *= (lane &  2) ? rdlane(sv, r*NQ+4) : rdlane(cv, r*NQ+4);
      a *= (lane &  1) ? rdlane(sv, r*NQ+5) : rdlane(cv, r*NQ+5);
      re[r] = a;
      im[r] = 0.0f;
    }

    // ---- 3 entangling layers (ranges 1, 2, 1); coef read per gate ----
    {
      gate2<0>(re, im, coef[0],  sgn[0], lane);
      gate2<1>(re, im, coef[1],  sgn[1], lane);
      gate2<2>(re, im, coef[2],  sgn[2], lane);
      gate2<3>(re, im, coef[3],  sgn[3], lane);
      gate2<4>(re, im, coef[4],  sgn[4], lane);
      gate2<5>(re, im, coef[5],  sgn[5], lane);
      #pragma unroll
      for (int r = 0; r < NB; ++r) {
        re[r] = __int_as_float(__builtin_amdgcn_ds_bpermute(pa1, __float_as_int(re[r])));
        im[r] = __int_as_float(__builtin_amdgcn_ds_bpermute(pa1, __float_as_int(im[r])));
      }
      gate2<0>(re, im, coef[6],  sgn[0], lane);
      gate2<1>(re, im, coef[7],  sgn[1], lane);
      gate2<2>(re, im, coef[8],  sgn[2], lane);
      gate2<3>(re, im, coef[9],  sgn[3], lane);
      gate2<4>(re, im, coef[10], sgn[4], lane);
      gate2<5>(re, im, coef[11], sgn[5], lane);
      #pragma unroll
      for (int r = 0; r < NB; ++r) {
        re[r] = __int_as_float(__builtin_amdgcn_ds_bpermute(pa2, __float_as_int(re[r])));
        im[r] = __int_as_float(__builtin_amdgcn_ds_bpermute(pa2, __float_as_int(im[r])));
      }
      gate2<0>(re, im, coef[12], sgn[0], lane);
      gate2<1>(re, im, coef[13], sgn[1], lane);
      gate2<2>(re, im, coef[14], sgn[2], lane);
      gate2<3>(re, im, coef[15], sgn[3], lane);
      gate2<4>(re, im, coef[16], sgn[4], lane);
      gate2<5>(re, im, coef[17], sgn[5], lane);
      #pragma unroll
      for (int r = 0; r < NB; ++r) {
        re[r] = __int_as_float(__builtin_amdgcn_ds_bpermute(pa1, __float_as_int(re[r])));
        im[r] = __int_as_float(__builtin_amdgcn_ds_bpermute(pa1, __float_as_int(im[r])));
      }
    }

    // ---- measurement + classifier head ----
    const float p0 = fmaf(re[0], re[0], im[0] * im[0]);
    const float p1 = fmaf(re[1], re[1], im[1] * im[1]);
    float v0 = 0.0f, v1 = 0.0f;
    #pragma unroll
    for (int j = 0; j < 5; ++j) {
      const float gj = lc[(9 + j) * 64 + lane];
      const float o0 = bcast63(red_sum(p0 * gj));
      const float o1 = bcast63(red_sum(p1 * gj));
      v0 = (lane == j) ? o0 : v0;
      v1 = (lane == j) ? o1 : v1;
    }
    if (lane < 5) {
      out[(size_t)t0 * 5 + lane] = v0 + bcv;
      if (t0 + 1 < B) out[(size_t)(t0 + 1) * 5 + lane] = v1 + bcv;
    }
  }
}

extern "C" void kernel_launch(void* const* d_in, const int* in_sizes, int n_in,
                              void* d_out, int out_size, void* d_ws, size_t ws_size,
                              hipStream_t stream) {
  const float* x     = (const float*)d_in[0];
  const float* W1    = (const float*)d_in[1];
  const float* b1    = (const float*)d_in[2];
  const float* ln_g  = (const float*)d_in[3];
  const float* ln_b  = (const float*)d_in[4];
  const float* W2    = (const float*)d_in[5];
  const float* b2    = (const float*)d_in[6];
  const float* th_sh = (const float*)d_in[7];
  const float* th_tk = (const float*)d_in[8];
  const float* Wc    = (const float*)d_in[9];
  const float* bc    = (const float*)d_in[10];
  float* out = (float*)d_out;

  const int B = in_sizes[0] / DIM;
  int blocks = (B + 4 * NB - 1) / (4 * NB);
  if (blocks > 2048) blocks = 2048;
  qmaml_v5<<<blocks, 256, 0, stream>>>(x, W1, b1, ln_g, ln_b, W2, b2,
                                       th_sh, th_tk, Wc, bc, out, B);
}

// Round 6
// 86.471 us; speedup vs baseline: 4.4858x; 4.4858x over previous
//
#include <hip/hip_runtime.h>
#include <math.h>

#define NQ 6
#define DIM 64
#define NB 2             // elements per wave-iteration
#define PI_F 3.14159265358979323846f

typedef int i32x2 __attribute__((ext_vector_type(2)));

// ---------- DPP helpers ----------
template <int CTRL, int ROWM, bool BC>
__device__ __forceinline__ float dpp_add_src(float v) {
  int r = __builtin_amdgcn_update_dpp(0, __float_as_int(v), CTRL, ROWM, 0xF, BC);
  return __int_as_float(r);
}
template <int CTRL>
__device__ __forceinline__ float dpp_mov(float v) {
  int i = __float_as_int(v);
  return __int_as_float(__builtin_amdgcn_update_dpp(i, i, CTRL, 0xF, 0xF, false));
}

// sum over 64 lanes; valid in lane 63 (AMD-standard DPP ladder, R2-proven)
__device__ __forceinline__ float red_sum(float v) {
  v += dpp_add_src<0x111, 0xF, true>(v);   // row_shr:1
  v += dpp_add_src<0x112, 0xF, true>(v);   // row_shr:2
  v += dpp_add_src<0x114, 0xF, true>(v);   // row_shr:4
  v += dpp_add_src<0x118, 0xF, true>(v);   // row_shr:8
  v += dpp_add_src<0x142, 0xA, false>(v);  // row_bcast:15 -> rows 1,3
  v += dpp_add_src<0x143, 0xC, false>(v);  // row_bcast:31 -> rows 2,3
  return v;
}
__device__ __forceinline__ float bcast63(float v) {
  return __int_as_float(__builtin_amdgcn_readlane(__float_as_int(v), 63));
}
__device__ __forceinline__ float rdlane(float v, int l) {
  return __int_as_float(__builtin_amdgcn_readlane(__float_as_int(v), l));
}

// ---------- xor-partner exchange for wire W (mask = 32>>W) ----------
// All VALU except nothing: xor4 via ror4/ror12 + select.
// Convention anchor: red_sum's row_shr accumulates toward lane 63, so
// row_ror:n delivers lane (i-n) mod 16. Lane needing i^4 = i-4 (bit4 set)
// takes ror:4; lane needing i+4 = i-12 mod 16 takes ror:12.
template <int W>
__device__ __forceinline__ float shuf(float v, int lane) {
  if constexpr (W == 5) {        // xor 1: quad_perm [1,0,3,2]
    return dpp_mov<0xB1>(v);
  } else if constexpr (W == 4) { // xor 2: quad_perm [2,3,0,1]
    return dpp_mov<0x4E>(v);
  } else if constexpr (W == 3) { // xor 4: select(ror4, ror12)
    const float r4  = dpp_mov<0x124>(v);
    const float r12 = dpp_mov<0x12C>(v);
    return (lane & 4) ? r4 : r12;
  } else if constexpr (W == 2) { // xor 8 == row_ror:8
    return dpp_mov<0x128>(v);
  } else if constexpr (W == 1) { // xor 16: permlane16_swap (VALU, R4-proven)
#if __has_builtin(__builtin_amdgcn_permlane16_swap)
    i32x2 r = __builtin_amdgcn_permlane16_swap(__float_as_int(v),
                                               __float_as_int(v), false, false);
    return __int_as_float((lane & 16) ? r[0] : r[1]);
#else
    return __int_as_float(__builtin_amdgcn_ds_swizzle(__float_as_int(v), 0x401F));
#endif
  } else {                       // xor 32: permlane32_swap (VALU, R4-proven)
#if __has_builtin(__builtin_amdgcn_permlane32_swap)
    i32x2 r = __builtin_amdgcn_permlane32_swap(__float_as_int(v),
                                               __float_as_int(v), false, false);
    return __int_as_float((lane & 32) ? r[0] : r[1]);
#else
    return __shfl_xor(v, 32, 64);
#endif
  }
}

// ---------- one Rot gate on wire W applied to NB states ----------
// U = [[a,b],[-conj(b),conj(a)]]; c = (ar,ai,br,bi) wave-uniform (LDS bcast);
// sg = -1 on the |1> half of the wire.
template <int W>
__device__ __forceinline__ void gate2(float (&re)[NB], float (&im)[NB],
                                      float4 c, float sg, int lane) {
  const float ais = c.y * sg;
  const float brs = c.z * sg;
  #pragma unroll
  for (int r = 0; r < NB; ++r) {
    const float pr = shuf<W>(re[r], lane);
    const float pi = shuf<W>(im[r], lane);
    float nr = c.x * re[r];
    nr = fmaf(-ais, im[r], nr);
    nr = fmaf(brs, pr, nr);
    nr = fmaf(-c.w, pi, nr);
    float ni = c.x * im[r];
    ni = fmaf(ais, re[r], ni);
    ni = fmaf(brs, pi, ni);
    ni = fmaf(c.w, pr, ni);
    re[r] = nr; im[r] = ni;
  }
}

// composed source index for the CNOT ring of range r
__device__ __forceinline__ int cnot_src(int j, int r) {
  int i = j;
  #pragma unroll
  for (int w = 5; w >= 0; --w) {
    const int cm = 32 >> w;
    const int tm = 32 >> ((w + r) % NQ);
    if (i & cm) i ^= tm;
  }
  return i;
}

__global__ __launch_bounds__(256) void qmaml_v6(
    const float* __restrict__ x,
    const float* __restrict__ W1,
    const float* __restrict__ b1,
    const float* __restrict__ ln_g,
    const float* __restrict__ ln_b,
    const float* __restrict__ W2,
    const float* __restrict__ b2,
    const float* __restrict__ th_sh,
    const float* __restrict__ th_tk,
    const float* __restrict__ Wc,
    const float* __restrict__ bc,
    float* __restrict__ out,
    int B)
{
  // W1^T in float4 chunks: w1t4[k4*64 + j] = {W1[j][4k4+0..3]}  (16 KiB)
  __shared__ float4 w1t4[16 * 64];
  __shared__ float4 coef[18];

  const int tid = threadIdx.x;

  #pragma unroll
  for (int it = 0; it < 4; ++it) {
    const int idx = tid + it * 256;          // global float4 index = j*16 + k4
    w1t4[(idx & 15) * 64 + (idx >> 4)] = reinterpret_cast<const float4*>(W1)[idx];
  }
  if (tid < 18) {
    const int layer = tid / 6, w = tid % 6;
    const float* th = (layer < 2) ? (th_sh + (layer * 6 + w) * 3)
                                  : (th_tk + w * 3);
    const float phi = th[0], the = th[1], om = th[2];
    float S, C;   sincosf(0.5f * the,        &S,  &C);
    float sS, cS; sincosf(0.5f * (om + phi), &sS, &cS);
    float sD, cD; sincosf(0.5f * (om - phi), &sD, &cD);
    coef[tid] = make_float4(C * cS, -C * sS, -S * cD, S * sD);
  }
  __syncthreads();

  const int lane = tid & 63;
  const int wid = __builtin_amdgcn_readfirstlane(blockIdx.x * 4 + (tid >> 6));
  const int nw = gridDim.x * 4;

  // ---- batch-independent per-lane preloads (R2-style, registers) ----
  const float b1v = b1[lane];
  const float lgv = ln_g[lane];
  const float lbv = ln_b[lane];
  float w2v[NQ];
  #pragma unroll
  for (int m = 0; m < NQ; ++m) w2v[m] = W2[m * DIM + lane];
  const float b2p = (lane < NB * NQ) ? b2[lane % NQ] : 0.0f;
  const float bcv = (lane < 5) ? bc[lane] : 0.0f;
  float sgn[NQ];
  #pragma unroll
  for (int w = 0; w < NQ; ++w) sgn[w] = (lane & (32 >> w)) ? -1.0f : 1.0f;
  float g5[5];
  #pragma unroll
  for (int j = 0; j < 5; ++j) {
    float a = 0.0f;
    #pragma unroll
    for (int w = 0; w < NQ; ++w) {
      const float wc = Wc[j * NQ + w];
      a += (lane & (32 >> w)) ? -wc : wc;
    }
    g5[j] = a;
  }
  const int pa1 = cnot_src(lane, 1) << 2;
  const int pa2 = cnot_src(lane, 2) << 2;

  for (int t0 = wid * NB; t0 < B; t0 += nw * NB) {
    // ---- Linear1 + ReLU for 2 elements; W1 chunk read once per k4 ----
    const float* __restrict__ xr0 = x + (size_t)t0 * DIM;      // wave-uniform
    const float* __restrict__ xr1 = xr0 + ((t0 + 1 < B) ? DIM : 0);
    float acc0 = b1v, acc1 = b1v;
    #pragma unroll
    for (int k4 = 0; k4 < 16; ++k4) {
      const float4 wv = w1t4[k4 * 64 + lane];
      acc0 = fmaf(wv.x, xr0[4*k4+0], acc0);
      acc0 = fmaf(wv.y, xr0[4*k4+1], acc0);
      acc0 = fmaf(wv.z, xr0[4*k4+2], acc0);
      acc0 = fmaf(wv.w, xr0[4*k4+3], acc0);
      acc1 = fmaf(wv.x, xr1[4*k4+0], acc1);
      acc1 = fmaf(wv.y, xr1[4*k4+1], acc1);
      acc1 = fmaf(wv.z, xr1[4*k4+2], acc1);
      acc1 = fmaf(wv.w, xr1[4*k4+3], acc1);
    }

    // ---- LayerNorm (4 independent DPP chains) ----
    float h[NB];
    {
      const float hv0 = fmaxf(acc0, 0.0f);
      const float hv1 = fmaxf(acc1, 0.0f);
      const float s10 = bcast63(red_sum(hv0)) * (1.0f / DIM);
      const float s20 = bcast63(red_sum(hv0 * hv0)) * (1.0f / DIM);
      const float s11 = bcast63(red_sum(hv1)) * (1.0f / DIM);
      const float s21 = bcast63(red_sum(hv1 * hv1)) * (1.0f / DIM);
      const float rs0 = __builtin_amdgcn_rsqf(s20 - s10 * s10 + 1e-5f);
      const float rs1 = __builtin_amdgcn_rsqf(s21 - s11 * s11 + 1e-5f);
      h[0] = fmaf((hv0 - s10) * rs0, lgv, lbv);
      h[1] = fmaf((hv1 - s11) * rs1, lgv, lbv);
    }

    // ---- Linear2: pack the 12 angle sums into lanes 0..11 ----
    float y = 0.0f;
    #pragma unroll
    for (int m = 0; m < NQ; ++m) {
      const float s0 = bcast63(red_sum(w2v[m] * h[0]));
      const float s1 = bcast63(red_sum(w2v[m] * h[1]));
      y = (lane == 0 * NQ + m) ? s0 : y;
      y = (lane == 1 * NQ + m) ? s1 : y;
    }
    y += b2p;

    // ---- tanh + half-angle sincos: one evaluation for both elements ----
    const float e = __expf(2.0f * y);
    const float tz = fmaf(-2.0f, __builtin_amdgcn_rcpf(e + 1.0f), 1.0f);
    const float ha = (0.5f * PI_F) * tz;
    const float sv = __sinf(ha);
    const float cv = __cosf(ha);

    // ---- init product states (lane = basis index) ----
    float re[NB], im[NB];
    #pragma unroll
    for (int r = 0; r < NB; ++r) {
      float a = (lane & 32) ? rdlane(sv, r*NQ+0) : rdlane(cv, r*NQ+0);
      a *= (lane & 16) ? rdlane(sv, r*NQ+1) : rdlane(cv, r*NQ+1);
      a *= (lane &  8) ? rdlane(sv, r*NQ+2) : rdlane(cv, r*NQ+2);
      a *= (lane &  4) ? rdlane(sv, r*NQ+3) : rdlane(cv, r*NQ+3);
      a *= (lane &  2) ? rdlane(sv, r*NQ+4) : rdlane(cv, r*NQ+4);
      a *= (lane &  1) ? rdlane(sv, r*NQ+5) : rdlane(cv, r*NQ+5);
      re[r] = a;
      im[r] = 0.0f;
    }

    // ---- 3 entangling layers (ranges 1, 2, 1) ----
    gate2<0>(re, im, coef[0],  sgn[0], lane);
    gate2<1>(re, im, coef[1],  sgn[1], lane);
    gate2<2>(re, im, coef[2],  sgn[2], lane);
    gate2<3>(re, im, coef[3],  sgn[3], lane);
    gate2<4>(re, im, coef[4],  sgn[4], lane);
    gate2<5>(re, im, coef[5],  sgn[5], lane);
    #pragma unroll
    for (int r = 0; r < NB; ++r) {
      re[r] = __int_as_float(__builtin_amdgcn_ds_bpermute(pa1, __float_as_int(re[r])));
      im[r] = __int_as_float(__builtin_amdgcn_ds_bpermute(pa1, __float_as_int(im[r])));
    }
    gate2<0>(re, im, coef[6],  sgn[0], lane);
    gate2<1>(re, im, coef[7],  sgn[1], lane);
    gate2<2>(re, im, coef[8],  sgn[2], lane);
    gate2<3>(re, im, coef[9],  sgn[3], lane);
    gate2<4>(re, im, coef[10], sgn[4], lane);
    gate2<5>(re, im, coef[11], sgn[5], lane);
    #pragma unroll
    for (int r = 0; r < NB; ++r) {
      re[r] = __int_as_float(__builtin_amdgcn_ds_bpermute(pa2, __float_as_int(re[r])));
      im[r] = __int_as_float(__builtin_amdgcn_ds_bpermute(pa2, __float_as_int(im[r])));
    }
    gate2<0>(re, im, coef[12], sgn[0], lane);
    gate2<1>(re, im, coef[13], sgn[1], lane);
    gate2<2>(re, im, coef[14], sgn[2], lane);
    gate2<3>(re, im, coef[15], sgn[3], lane);
    gate2<4>(re, im, coef[16], sgn[4], lane);
    gate2<5>(re, im, coef[17], sgn[5], lane);
    #pragma unroll
    for (int r = 0; r < NB; ++r) {
      re[r] = __int_as_float(__builtin_amdgcn_ds_bpermute(pa1, __float_as_int(re[r])));
      im[r] = __int_as_float(__builtin_amdgcn_ds_bpermute(pa1, __float_as_int(im[r])));
    }

    // ---- measurement + classifier head ----
    const float p0 = fmaf(re[0], re[0], im[0] * im[0]);
    const float p1 = fmaf(re[1], re[1], im[1] * im[1]);
    float v0 = 0.0f, v1 = 0.0f;
    #pragma unroll
    for (int j = 0; j < 5; ++j) {
      const float o0 = bcast63(red_sum(p0 * g5[j]));
      const float o1 = bcast63(red_sum(p1 * g5[j]));
      v0 = (lane == j) ? o0 : v0;
      v1 = (lane == j) ? o1 : v1;
    }
    if (lane < 5) {
      out[(size_t)t0 * 5 + lane] = v0 + bcv;
      if (t0 + 1 < B) out[(size_t)(t0 + 1) * 5 + lane] = v1 + bcv;
    }
  }
}

extern "C" void kernel_launch(void* const* d_in, const int* in_sizes, int n_in,
                              void* d_out, int out_size, void* d_ws, size_t ws_size,
                              hipStream_t stream) {
  const float* x     = (const float*)d_in[0];
  const float* W1    = (const float*)d_in[1];
  const float* b1    = (const float*)d_in[2];
  const float* ln_g  = (const float*)d_in[3];
  const float* ln_b  = (const float*)d_in[4];
  const float* W2    = (const float*)d_in[5];
  const float* b2    = (const float*)d_in[6];
  const float* th_sh = (const float*)d_in[7];
  const float* th_tk = (const float*)d_in[8];
  const float* Wc    = (const float*)d_in[9];
  const float* bc    = (const float*)d_in[10];
  float* out = (float*)d_out;

  const int B = in_sizes[0] / DIM;
  int blocks = (B + 4 * NB - 1) / (4 * NB);
  if (blocks > 2048) blocks = 2048;
  qmaml_v6<<<blocks, 256, 0, stream>>>(x, W1, b1, ln_g, ln_b, W2, b2,
                                       th_sh, th_tk, Wc, bc, out, B);
}